// Round 1
// 9090.560 us; speedup vs baseline: 1.2578x; 1.2578x over previous
//
#include <hip/hip_runtime.h>
#include <hip/hip_cooperative_groups.h>
#include <stdint.h>

namespace cg = cooperative_groups;

#define T_STEPS 512
#define BATCH   128
#define NN      1024
#define ALPHA_C 0.1f
#define DT_C    0.01f

// d_ws float offsets
#define OFF_BUFA 0
#define OFF_BUFB (BATCH*NN)                   // 131072
#define OFF_PART (2*BATCH*NN)                 // 262144  ([2][128][2][64] f32)
#define OFF_BAR  (OFF_PART + 2*BATCH*2*64)    // 294912  barrier counters

// Monotonic-counter barrier for a group of blocks (verified structure).
__device__ __forceinline__ void group_barrier(unsigned* cnt, unsigned target, int tid) {
    __syncthreads();
    if (tid == 0) {
        __hip_atomic_fetch_add(cnt, 1u, __ATOMIC_RELEASE, __HIP_MEMORY_SCOPE_AGENT);
        while (__hip_atomic_load(cnt, __ATOMIC_ACQUIRE, __HIP_MEMORY_SCOPE_AGENT) < target)
            __builtin_amdgcn_s_sleep(1);
    }
    __syncthreads();
}

typedef __attribute__((address_space(1))) const void gvoid_t;
typedef __attribute__((address_space(3))) void lvoid_t;
// direct global->LDS, 16B per lane; LDS dest is wave-uniform base + lane*16
#define GLOAD_LDS16(gp, lp) \
    __builtin_amdgcn_global_load_lds((gvoid_t*)(gp), (lvoid_t*)(lp), 16, 0, 0)

// 256 blocks x 512 threads. Block (g = bid&63 -> 16 n-cols, bb = bid>>6 -> 32 batches).
// Thread tile: 4 n x 8 b, k-split 32 (kk = tid&31, k4 = c*32+kk for chunk c=0..7).
// W_hh*mask held in 128 VGPRs per thread (constant across steps -> zero LDS W traffic).
// R (prev r1) staged global->LDS once per step via global_load_lds, consumed per
// 128-k chunk with counted vmcnt + raw s_barrier (T3/T4 pattern). k-split reduced
// with a 31-shuffle value-splitting butterfly; lane kk ends owning output
// (b = gb0 + gbq*8 + (kk>>2), n = g*16 + gn*4 + (kk&3)) -> x1 state stays per-thread.
__launch_bounds__(512, 2)
__global__ void rnn_step_kernel(const float* __restrict__ X,
                                const float* __restrict__ Xpert,
                                const float* __restrict__ popto,
                                const float* __restrict__ hidden0,
                                const float* __restrict__ W_hh,
                                const float* __restrict__ W_ih,
                                const float* __restrict__ W_fb,
                                const float* __restrict__ b_fb,
                                const float* __restrict__ W_out,
                                const float* __restrict__ b_out,
                                const float* __restrict__ mask_fb,
                                const float* __restrict__ mask_rec,
                                float* __restrict__ out,
                                float* __restrict__ ws)
{
    __shared__ __align__(16) float Rlds[8*32*128];   // 128 KB: [chunk][b][128 k]
    __shared__ __align__(16) float pbuf[32*2*4];     // [b][o][gn] vt partials
    __shared__ float v1s[32][2];

    const int tid = threadIdx.x;
    const int gn  = tid >> 7;          // 0..3  n-quad group
    const int gbq = (tid >> 5) & 3;    // 0..3  batch-octet group
    const int kk  = tid & 31;          // k-slice within chunk
    const int g   = blockIdx.x & 63;
    const int bb  = blockIdx.x >> 6;
    const int gb0 = bb * 32;
    const int b_loc = gbq*8 + (kk>>2);
    const int b_own = gb0 + b_loc;
    const int n_own = g*16 + gn*4 + (kk&3);

    float* bufA = ws + OFF_BUFA;
    float* bufB = ws + OFF_BUFB;
    float* part = ws + OFF_PART;
    unsigned* barArea = (unsigned*)(ws + OFF_BAR);
    unsigned* myBar   = barArea + bb * 32;

    if (blockIdx.x == 0 && tid < 4)
        __hip_atomic_store(barArea + tid*32, 0u, __ATOMIC_RELAXED, __HIP_MEMORY_SCOPE_AGENT);

    // ---- per-output constants (for this thread's owned output) ----
    const float wout0 = W_out[n_own];
    const float wout1 = W_out[NN + n_own];
    const float wfb0  = W_fb[n_own*2+0] * mask_fb[n_own*2+0];
    const float wfb1  = W_fb[n_own*2+1] * mask_fb[n_own*2+1];
    const float wih0  = W_ih[n_own*3+0];
    const float wih1  = W_ih[n_own*3+1];
    const float wih2  = W_ih[n_own*3+2];
    const float bfbv  = b_fb[n_own];
    const float bo0 = b_out[0], bo1 = b_out[1];

    // ---- W into registers: w4[c][i] = (W_hh*mask)[g*16+gn*4+i][(c*32+kk)*4 ..+4] ----
    const float4* Wh4 = (const float4*)W_hh;
    const float4* Mr4 = (const float4*)mask_rec;
    float4 w4[8][4];
    #pragma unroll
    for (int c = 0; c < 8; ++c) {
        #pragma unroll
        for (int i = 0; i < 4; ++i) {
            const int idx = (g*16 + gn*4 + i)*256 + c*32 + kk;
            const float4 wv = Wh4[idx], mv = Mr4[idx];
            w4[c][i] = make_float4(wv.x*mv.x, wv.y*mv.y, wv.z*mv.z, wv.w*mv.w);
        }
    }

    // ---- init: x1, r1_init -> bufA, parity-0 vt partials ----
    float x1 = hidden0[(size_t)b_own*NN + n_own];
    {
        const float r1i = fmaxf(x1, 0.f);
        bufA[(size_t)b_own*NN + n_own] = r1i;
        float p0 = r1i * wout0, p1 = r1i * wout1;
        p0 += __shfl_xor(p0, 1); p0 += __shfl_xor(p0, 2);
        p1 += __shfl_xor(p1, 1); p1 += __shfl_xor(p1, 2);
        if ((kk & 3) == 0) {
            pbuf[(b_loc*2+0)*4 + gn] = p0;
            pbuf[(b_loc*2+1)*4 + gn] = p1;
        }
    }
    __syncthreads();
    if (tid < 64) {
        const int b = tid >> 1, o = tid & 1;
        const float4 q = ((const float4*)pbuf)[b*2 + o];
        part[((0*BATCH + gb0 + b)*2 + o)*64 + g] = q.x + q.y + q.z + q.w;
    }

    cg::this_grid().sync();            // covers bufA (cross-block), part, counters

    float* Hout = out + (size_t)T_STEPS * BATCH * 2;

    for (int s = 0; s <= T_STEPS + 1; ++s) {
        const int pr = s & 1;
        float extrabase = 0.f;

        if (s <= T_STEPS) {
            // A) per-output input terms; loads issued BEFORE staging (oldest in vmcnt FIFO)
            const int cur = (s == 0) ? 0 : (s - 1);
            const float* Xc = X + (size_t)(cur*BATCH + b_own) * 7;
            const float pop = popto[(size_t)cur*BATCH*NN + (size_t)b_own*NN + n_own];
            extrabase = fmaf(Xc[0], wih0, fmaf(Xc[1], wih1, fmaf(Xc[2], wih2, bfbv))) + pop;
            asm volatile("" ::: "memory");   // pin: extra loads issue before staging

            // B) stage prev r1 [gb0, gb0+32) x [0,1024) -> Rlds[chunk][b][k]
            const float* Rsrc = (s == 0) ? bufA : (s == 1) ? bufB
                              : Hout + (size_t)(s-2)*BATCH*NN;
            const float* base0 = Rsrc + ((size_t)(gb0 + (tid >> 5)))*NN + kk*4;
            #pragma unroll
            for (int r = 0; r < 16; ++r) {   // round r: chunk r>>1, b-half r&1
                GLOAD_LDS16(base0 + (r&1)*(16*NN) + (r>>1)*128, &Rlds[r*2048 + tid*4]);
            }
            asm volatile("" ::: "memory");
        }

        // C) v1 phase, spread across all 8 waves: (b,o) = tid>>3, 8 lanes each
        {
            const int pi = tid >> 3, l8 = tid & 7;
            const int b = pi >> 1, o = pi & 1;
            const int gbv = gb0 + b;
            const float4* pp = (const float4*)&part[((pr*BATCH + gbv)*2 + o)*64];
            const float4 qa = pp[l8], qb = pp[l8 + 8];
            float sum = (qa.x+qa.y+qa.z+qa.w) + (qb.x+qb.y+qb.z+qb.w);
            sum += __shfl_xor(sum, 1);
            sum += __shfl_xor(sum, 2);
            sum += __shfl_xor(sum, 4);
            if (l8 == 0) {
                const float bo = o ? bo1 : bo0;
                float v1n;
                if (s == 0) {
                    v1n = sum + bo;                                   // v1_init
                } else {
                    const int tp = (s == 1) ? 0 : (s - 2);
                    const float vt = sum + bo + Xpert[((size_t)tp*BATCH + gbv)*2 + o];
                    v1n = v1s[b][o] + DT_C * (X[((size_t)tp*BATCH + gbv)*7 + 3 + o] - vt);
                    if (s >= 2 && g == 0)
                        out[(size_t)(s-2)*BATCH*2 + gbv*2 + o] = v1n; // poserr[s-2]
                }
                v1s[b][o] = v1n;
            }
        }
        if (s > T_STEPS) break;            // epilogue (s==513) only did poserr[511]

        // D) main matmul: 8 chunks of 128 k; per chunk: 1 k4 per lane x 8 b x 4 n
        float acc[32];
        #pragma unroll
        for (int v = 0; v < 32; ++v) acc[v] = 0.f;
        const float4* Rl4 = (const float4*)Rlds;
        const int rbase = gbq*256 + kk;

#define DO_CHUNK(c, waitstr) \
        asm volatile(waitstr "\n\ts_barrier" ::: "memory"); \
        { \
            _Pragma("unroll") \
            for (int j = 0; j < 8; ++j) { \
                const float4 rv = Rl4[(c)*1024 + rbase + j*32]; \
                _Pragma("unroll") \
                for (int i = 0; i < 4; ++i) { \
                    acc[j*4+i] = fmaf(w4[c][i].x, rv.x, acc[j*4+i]); \
                    acc[j*4+i] = fmaf(w4[c][i].y, rv.y, acc[j*4+i]); \
                    acc[j*4+i] = fmaf(w4[c][i].z, rv.z, acc[j*4+i]); \
                    acc[j*4+i] = fmaf(w4[c][i].w, rv.w, acc[j*4+i]); \
                } \
            } \
        }
        // lgkmcnt(0) on chunk 0 publishes v1s writes before the barrier
        DO_CHUNK(0, "s_waitcnt vmcnt(14) lgkmcnt(0)")
        DO_CHUNK(1, "s_waitcnt vmcnt(12)")
        DO_CHUNK(2, "s_waitcnt vmcnt(10)")
        DO_CHUNK(3, "s_waitcnt vmcnt(8)")
        DO_CHUNK(4, "s_waitcnt vmcnt(6)")
        DO_CHUNK(5, "s_waitcnt vmcnt(4)")
        DO_CHUNK(6, "s_waitcnt vmcnt(2)")
        DO_CHUNK(7, "s_waitcnt vmcnt(0)")
#undef DO_CHUNK

        // E) k-split reduce: value-splitting butterfly; lane kk keeps v==kk
        float r16[16];
        {
            const bool h = (kk & 16);
            #pragma unroll
            for (int p = 0; p < 16; ++p) {
                const float keep = h ? acc[p+16] : acc[p];
                const float send = h ? acc[p]    : acc[p+16];
                r16[p] = keep + __shfl_xor(send, 16);
            }
        }
        {
            const bool h = (kk & 8);
            #pragma unroll
            for (int p = 0; p < 8; ++p) {
                const float keep = h ? r16[p+8] : r16[p];
                const float send = h ? r16[p]   : r16[p+8];
                r16[p] = keep + __shfl_xor(send, 8);
            }
        }
        {
            const bool h = (kk & 4);
            #pragma unroll
            for (int p = 0; p < 4; ++p) {
                const float keep = h ? r16[p+4] : r16[p];
                const float send = h ? r16[p]   : r16[p+4];
                r16[p] = keep + __shfl_xor(send, 4);
            }
        }
        {
            const bool h = (kk & 2);
            #pragma unroll
            for (int p = 0; p < 2; ++p) {
                const float keep = h ? r16[p+2] : r16[p];
                const float send = h ? r16[p]   : r16[p+2];
                r16[p] = keep + __shfl_xor(send, 2);
            }
        }
        float pre_dot;
        {
            const bool h = (kk & 1);
            const float keep = h ? r16[1] : r16[0];
            const float send = h ? r16[0] : r16[1];
            pre_dot = keep + __shfl_xor(send, 1);
        }

        // F) epilogue: state update for this thread's owned output
        float fb = 0.f;
        if (s >= 2) fb = v1s[b_loc][0]*wfb0 + v1s[b_loc][1]*wfb1;  // j==0 & warmup: zero
        const float pre = pre_dot + extrabase + fb;
        x1 = x1 + ALPHA_C * (pre - x1);
        const float r1 = fmaxf(x1, 0.f);
        float* dst = (s == 0) ? bufB : (Hout + (size_t)(s-1)*BATCH*NN);
        dst[(size_t)b_own*NN + n_own] = r1;                        // hidden1[s-1] for s>=1

        // vt partials for this step (parity pw): quad-reduce over 4 n, then gn via pbuf
        {
            float p0 = r1 * wout0, p1 = r1 * wout1;
            p0 += __shfl_xor(p0, 1); p0 += __shfl_xor(p0, 2);
            p1 += __shfl_xor(p1, 1); p1 += __shfl_xor(p1, 2);
            if ((kk & 3) == 0) {
                pbuf[(b_loc*2+0)*4 + gn] = p0;
                pbuf[(b_loc*2+1)*4 + gn] = p1;
            }
        }
        asm volatile("s_waitcnt lgkmcnt(0)\n\ts_barrier" ::: "memory");
        if (tid < 64) {
            const int b = tid >> 1, o = tid & 1;
            const float4 q = ((const float4*)pbuf)[b*2 + o];
            const int pw = (s + 1) & 1;
            part[((pw*BATCH + gb0 + b)*2 + o)*64 + g] = q.x + q.y + q.z + q.w;
        }
        group_barrier(myBar, 64u * (unsigned)(s + 1), tid);
    }
}

extern "C" void kernel_launch(void* const* d_in, const int* in_sizes, int n_in,
                              void* d_out, int out_size, void* d_ws, size_t ws_size,
                              hipStream_t stream) {
    (void)in_sizes; (void)n_in; (void)out_size; (void)ws_size;
    const float* X        = (const float*)d_in[0];
    const float* Xpert    = (const float*)d_in[1];
    const float* popto    = (const float*)d_in[2];
    const float* hidden0  = (const float*)d_in[3];
    const float* W_hh     = (const float*)d_in[4];
    const float* W_ih     = (const float*)d_in[5];
    const float* W_fb     = (const float*)d_in[6];
    const float* b_fb     = (const float*)d_in[7];
    const float* W_out    = (const float*)d_in[8];
    const float* b_out    = (const float*)d_in[9];
    const float* mask_fb  = (const float*)d_in[10];
    const float* mask_rec = (const float*)d_in[11];
    float* out = (float*)d_out;
    float* ws  = (float*)d_ws;

    void* args[] = { &X, &Xpert, &popto, &hidden0, &W_hh, &W_ih, &W_fb, &b_fb,
                     &W_out, &b_out, &mask_fb, &mask_rec, &out, &ws };
    (void)hipLaunchCooperativeKernel((const void*)rnn_step_kernel, dim3(256), dim3(512, 1, 1),
                                     args, 0, stream);
}